// Round 5
// baseline (894.819 us; speedup 1.0000x reference)
//
#include <hip/hip_runtime.h>
#include <math.h>

// ---------------------------------------------------------------------------
// GATv2 x2 on MI355X.
// New path (ws permitting):
//   memset -> count_deg -> scan1/2/3 -> scatter(CSR) -> gemm1(xl bf16, xr f32)
//   -> k_edge (qe1=ea@We1 bf16 [CSR order], qe2=ea@We2 f32, src_perm)
//   -> k_fused1_q (softmax+aggregate+lrelu+gemv2; self-term = in-loop qe1 mean)
//   -> k_fused2_q (softmax+aggregate+head-mean;   self-term = in-loop qe2 mean)
// Fallback path (small ws): round-4 kernels (ea_all/loopq based).
// ---------------------------------------------------------------------------

static __device__ __forceinline__ ushort f2bf(float f) {
    unsigned u = __float_as_uint(f);
    unsigned r = (u + 0x7fffu + ((u >> 16) & 1u)) >> 16;  // RNE
    return (ushort)r;
}

// sum across each 16-lane row via DPP row_ror (pure VALU, no DS)
static __device__ __forceinline__ float row_sum16(float x) {
    x += __int_as_float(__builtin_amdgcn_update_dpp(0, __float_as_int(x), 0x121, 0xf, 0xf, true));
    x += __int_as_float(__builtin_amdgcn_update_dpp(0, __float_as_int(x), 0x122, 0xf, 0xf, true));
    x += __int_as_float(__builtin_amdgcn_update_dpp(0, __float_as_int(x), 0x124, 0xf, 0xf, true));
    x += __int_as_float(__builtin_amdgcn_update_dpp(0, __float_as_int(x), 0x128, 0xf, 0xf, true));
    return x;
}

static __device__ __forceinline__ float red64(float x) {  // 64-lane sum
    x = row_sum16(x);
    x += __shfl_xor(x, 16);
    x += __shfl_xor(x, 32);
    return x;
}

__global__ void k_count_deg(const int* __restrict__ dst, int* __restrict__ deg, int E) {
    int i = blockIdx.x * blockDim.x + threadIdx.x;
    if (i < E) atomicAdd(&deg[dst[i]], 1);
}

__global__ __launch_bounds__(1024) void k_scan1(const int* __restrict__ deg,
                                                int* __restrict__ rowptr,
                                                int* __restrict__ part, int N) {
    __shared__ int wsum[16];
    int t = threadIdx.x, l = t & 63, w = t >> 6;
    int i = blockIdx.x * 1024 + t;
    int v = (i < N) ? deg[i] : 0;
    int sc = v;
    #pragma unroll
    for (int off = 1; off < 64; off <<= 1) {
        int y = __shfl_up(sc, off);
        if (l >= off) sc += y;
    }
    if (l == 63) wsum[w] = sc;
    __syncthreads();
    if (w == 0) {
        int pv = (l < 16) ? wsum[l] : 0;
        int psc = pv;
        #pragma unroll
        for (int off = 1; off < 16; off <<= 1) {
            int y = __shfl_up(psc, off);
            if (l >= off) psc += y;
        }
        if (l < 16) wsum[l] = psc - pv;
    }
    __syncthreads();
    if (i < N) rowptr[i] = wsum[w] + sc - v;
    if (t == 1023) part[blockIdx.x] = wsum[15] + sc;
}

__global__ void k_scan2(int* __restrict__ part, int nb) {
    int l = threadIdx.x & 63;
    int run = 0;
    for (int base = 0; base < nb; base += 64) {
        int i = base + l;
        int v = (i < nb) ? part[i] : 0;
        int sc = v;
        #pragma unroll
        for (int off = 1; off < 64; off <<= 1) {
            int y = __shfl_up(sc, off);
            if (l >= off) sc += y;
        }
        if (i < nb) part[i] = run + sc - v;
        run += __shfl(sc, 63);
    }
}

__global__ void k_scan3(int* __restrict__ rowptr, const int* __restrict__ part, int N, int E) {
    int i = blockIdx.x * 256 + threadIdx.x;
    if (i < N) rowptr[i] += part[i >> 10];
    if (i == 0) rowptr[N] = E;
}

__global__ void k_scatter(const int* __restrict__ dst, const int* __restrict__ rowptr,
                          int* __restrict__ cursor, int* __restrict__ csr, int E) {
    int i = blockIdx.x * blockDim.x + threadIdx.x;
    if (i < E) {
        int d = dst[i];
        int pos = rowptr[d] + atomicAdd(&cursor[d], 1);
        csr[pos] = i;
    }
}

// xl1 = x @ Wl1 (bf16 out), xr1 = x @ Wr1 (f32 out)
__global__ __launch_bounds__(256) void k_gemm1(const float* __restrict__ x,
                                               const float* __restrict__ Wl,
                                               const float* __restrict__ Wr,
                                               ushort* __restrict__ xl, float* __restrict__ xr,
                                               int N) {
    __shared__ float xs[32 * 128];
    int r0 = blockIdx.x * 32;
    int t = threadIdx.x;
    for (int i = t * 4; i < 32 * 128; i += 256 * 4) {
        int r = i >> 7;
        float4 v = make_float4(0.f, 0.f, 0.f, 0.f);
        if (r0 + r < N) v = *(const float4*)(&x[(size_t)(r0 + r) * 128 + (i & 127)]);
        *(float4*)(&xs[i]) = v;
    }
    __syncthreads();
    int c = t & 127;
    int rbase = (t >> 7) * 16;
    float accl[16], accr[16];
    #pragma unroll
    for (int r = 0; r < 16; ++r) { accl[r] = 0.f; accr[r] = 0.f; }
    for (int k = 0; k < 128; ++k) {
        float wl = Wl[k * 128 + c];
        float wr = Wr[k * 128 + c];
        #pragma unroll
        for (int r = 0; r < 16; ++r) {
            float xv = xs[(rbase + r) * 128 + k];
            accl[r] += xv * wl;
            accr[r] += xv * wr;
        }
    }
    #pragma unroll
    for (int r = 0; r < 16; ++r) {
        int row = r0 + rbase + r;
        if (row < N) {
            xl[(size_t)row * 128 + c] = f2bf(accl[r]);
            xr[(size_t)row * 128 + c] = accr[r];
        }
    }
}

// ======================= NEW PATH ==========================================

// per edge (wave per edge): qe1[j] = ea[csr[j]] @ We1 (bf16 x128),
// qe2[j] = ea @ We2 (f32 x4), src_perm[j] = src[csr[j]]
__global__ __launch_bounds__(256) void k_edge(
    const int* __restrict__ csr, const int* __restrict__ src,
    const float* __restrict__ ea, const float* __restrict__ We1,
    const float* __restrict__ We2,
    unsigned* __restrict__ qe1, float* __restrict__ qe2,
    int* __restrict__ src_perm, int E) {
    int t = threadIdx.x, l = t & 63;
    int j = (blockIdx.x * 256 + t) >> 6;
    if (j >= E) return;
    int e = csr[j];
    const float4* p4 = (const float4*)(ea + (size_t)e * 16);
    float4 b0 = p4[0], b1 = p4[1], b2 = p4[2], b3 = p4[3];
    float a[16] = {b0.x, b0.y, b0.z, b0.w, b1.x, b1.y, b1.z, b1.w,
                   b2.x, b2.y, b2.z, b2.w, b3.x, b3.y, b3.z, b3.w};
    float vx = 0.f, vy = 0.f;
    #pragma unroll
    for (int k = 0; k < 16; ++k) {
        float2 w = *(const float2*)(We1 + k * 128 + 2 * l);
        vx += a[k] * w.x;
        vy += a[k] * w.y;
    }
    qe1[(size_t)j * 64 + l] = (unsigned)f2bf(vx) | ((unsigned)f2bf(vy) << 16);
    if (l == 0) src_perm[j] = src[e];
    if (l < 4) {
        float q = 0.f;
        #pragma unroll
        for (int k = 0; k < 16; ++k) q += a[k] * We2[k * 4 + l];
        qe2[(size_t)j * 4 + l] = q;
    }
}

// layer 1 fused (wave per node, lane l owns channels 2l,2l+1), unroll-4,
// self-loop term = running mean of qe1 over incoming edges.
__global__ __launch_bounds__(256) void k_fused1_q(
    const int* __restrict__ rowptr, const int* __restrict__ src_perm,
    const ushort* __restrict__ xl_bf, const float* __restrict__ xr,
    const unsigned* __restrict__ qe1, const float* __restrict__ att,
    const float* __restrict__ Wl2, const float* __restrict__ Wr2,
    float* __restrict__ xl2, float* __restrict__ xr2, int N) {
    int t = threadIdx.x, l = t & 63;
    int n = (blockIdx.x * 256 + t) >> 6;
    if (n >= N) return;
    const float RLN2 = 1.44269504f;
    float2 av = *(const float2*)(att + 2 * l);
    av.x *= RLN2; av.y *= RLN2;
    float2 xrv = *(const float2*)(xr + (size_t)n * 128 + 2 * l);
    int rs = rowptr[n], re = rowptr[n + 1];
    int deg = re - rs;
    float acc0 = 0.f, acc1 = 0.f, den = 0.f, mq0 = 0.f, mq1 = 0.f;
    for (int base = 0; base < deg; base += 4) {
        int rowA[4];
        float mask[4];
        #pragma unroll
        for (int c = 0; c < 4; ++c) {
            int slot = base + c;
            bool valid = slot < deg;
            mask[c] = valid ? 1.f : 0.f;
            rowA[c] = valid ? rs + slot : rs;
        }
        int sA[4];
        #pragma unroll
        for (int c = 0; c < 4; ++c) sA[c] = src_perm[rowA[c]];
        unsigned qw[4];
        #pragma unroll
        for (int c = 0; c < 4; ++c) qw[c] = qe1[(size_t)rowA[c] * 64 + l];
        unsigned xw[4];
        #pragma unroll
        for (int c = 0; c < 4; ++c)
            xw[c] = *(const unsigned*)(xl_bf + (size_t)sA[c] * 128 + 2 * l);
        #pragma unroll
        for (int c = 0; c < 4; ++c) {
            float q0 = __uint_as_float(qw[c] << 16);
            float q1 = __uint_as_float(qw[c] & 0xffff0000u);
            float xl0 = __uint_as_float(xw[c] << 16);
            float xl1 = __uint_as_float(xw[c] & 0xffff0000u);
            float vx = xrv.x + xl0 + q0;
            float vy = xrv.y + xl1 + q1;
            vx = fmaxf(vx, 0.2f * vx);
            vy = fmaxf(vy, 0.2f * vy);
            float p = row_sum16(av.x * vx + av.y * vy);
            float w = exp2f(p) * mask[c];
            acc0 += w * xl0;
            acc1 += w * xl1;
            den += w;
            mq0 += mask[c] * q0;
            mq1 += mask[c] * q1;
        }
    }
    {   // self loop: qe_self = mean of incoming qe1
        float inv = 1.f / (float)(deg > 1 ? deg : 1);
        float q0 = mq0 * inv, q1 = mq1 * inv;
        unsigned xw = *(const unsigned*)(xl_bf + (size_t)n * 128 + 2 * l);
        float xl0 = __uint_as_float(xw << 16);
        float xl1 = __uint_as_float(xw & 0xffff0000u);
        float vx = xrv.x + xl0 + q0;
        float vy = xrv.y + xl1 + q1;
        vx = fmaxf(vx, 0.2f * vx);
        vy = fmaxf(vy, 0.2f * vy);
        float p = row_sum16(av.x * vx + av.y * vy);
        float w = exp2f(p);
        acc0 += w * xl0;
        acc1 += w * xl1;
        den += w;
    }
    float rdn = 1.f / (den + 1e-16f);
    float h0 = acc0 * rdn, h1 = acc1 * rdn;
    h0 = h0 > 0.f ? h0 : 0.01f * h0;
    h1 = h1 > 0.f ? h1 : 0.01f * h1;
    float4 wla = *(const float4*)(Wl2 + (size_t)(2 * l) * 4);
    float4 wlb = *(const float4*)(Wl2 + (size_t)(2 * l + 1) * 4);
    float4 wra = *(const float4*)(Wr2 + (size_t)(2 * l) * 4);
    float4 wrb = *(const float4*)(Wr2 + (size_t)(2 * l + 1) * 4);
    float q0 = red64(h0 * wla.x + h1 * wlb.x);
    float q1 = red64(h0 * wla.y + h1 * wlb.y);
    float q2 = red64(h0 * wla.z + h1 * wlb.z);
    float q3 = red64(h0 * wla.w + h1 * wlb.w);
    float q4 = red64(h0 * wra.x + h1 * wrb.x);
    float q5 = red64(h0 * wra.y + h1 * wrb.y);
    float q6 = red64(h0 * wra.z + h1 * wrb.z);
    float q7 = red64(h0 * wra.w + h1 * wrb.w);
    if (l == 0) {
        *(float4*)(xl2 + (size_t)n * 4) = make_float4(q0, q1, q2, q3);
        *(float4*)(xr2 + (size_t)n * 4) = make_float4(q4, q5, q6, q7);
    }
}

// layer 2 fused: 16 lanes per node, self-term = in-loop mean of qe2
__global__ __launch_bounds__(256) void k_fused2_q(
    const int* __restrict__ rowptr, const int* __restrict__ src_perm,
    const float* __restrict__ xl2, const float* __restrict__ xr2,
    const float* __restrict__ qe2, const float* __restrict__ att2,
    float* __restrict__ out, int N) {
    int t = threadIdx.x, l = t & 63, g = l & 15;
    int node = (((blockIdx.x * 256 + t) >> 6) << 2) + (l >> 4);
    if (node >= N) return;
    int rs = rowptr[node], re = rowptr[node + 1];
    int deg = re - rs;
    float4 xrv = *(const float4*)(xr2 + (size_t)node * 4);
    const float RLN2 = 1.44269504f;
    float a0 = att2[0] * RLN2, a1 = att2[1] * RLN2;
    float a2 = att2[2] * RLN2, a3 = att2[3] * RLN2;
    float ac0 = 0.f, ac1 = 0.f, ac2 = 0.f, ac3 = 0.f;
    float dn0 = 0.f, dn1 = 0.f, dn2 = 0.f, dn3 = 0.f;
    float mq0 = 0.f, mq1 = 0.f, mq2 = 0.f, mq3 = 0.f;
    for (int slot = g; slot < deg; slot += 16) {
        int row = rs + slot;
        int s = src_perm[row];
        float4 q = *(const float4*)(qe2 + (size_t)row * 4);
        float4 xv = *(const float4*)(xl2 + (size_t)s * 4);
        float v0 = xv.x + xrv.x + q.x; v0 = fmaxf(v0, 0.2f * v0);
        float v1 = xv.y + xrv.y + q.y; v1 = fmaxf(v1, 0.2f * v1);
        float v2 = xv.z + xrv.z + q.z; v2 = fmaxf(v2, 0.2f * v2);
        float v3 = xv.w + xrv.w + q.w; v3 = fmaxf(v3, 0.2f * v3);
        float w0 = exp2f(v0 * a0); ac0 += w0 * xv.x; dn0 += w0;
        float w1 = exp2f(v1 * a1); ac1 += w1 * xv.y; dn1 += w1;
        float w2 = exp2f(v2 * a2); ac2 += w2 * xv.z; dn2 += w2;
        float w3 = exp2f(v3 * a3); ac3 += w3 * xv.w; dn3 += w3;
        mq0 += q.x; mq1 += q.y; mq2 += q.z; mq3 += q.w;
    }
    ac0 = row_sum16(ac0); ac1 = row_sum16(ac1);
    ac2 = row_sum16(ac2); ac3 = row_sum16(ac3);
    dn0 = row_sum16(dn0); dn1 = row_sum16(dn1);
    dn2 = row_sum16(dn2); dn3 = row_sum16(dn3);
    mq0 = row_sum16(mq0); mq1 = row_sum16(mq1);
    mq2 = row_sum16(mq2); mq3 = row_sum16(mq3);
    {   // self loop (uniform across the 16-lane group)
        float inv = 1.f / (float)(deg > 1 ? deg : 1);
        float4 xv = *(const float4*)(xl2 + (size_t)node * 4);
        float v0 = xv.x + xrv.x + mq0 * inv; v0 = fmaxf(v0, 0.2f * v0);
        float v1 = xv.y + xrv.y + mq1 * inv; v1 = fmaxf(v1, 0.2f * v1);
        float v2 = xv.z + xrv.z + mq2 * inv; v2 = fmaxf(v2, 0.2f * v2);
        float v3 = xv.w + xrv.w + mq3 * inv; v3 = fmaxf(v3, 0.2f * v3);
        float w0 = exp2f(v0 * a0); ac0 += w0 * xv.x; dn0 += w0;
        float w1 = exp2f(v1 * a1); ac1 += w1 * xv.y; dn1 += w1;
        float w2 = exp2f(v2 * a2); ac2 += w2 * xv.z; dn2 += w2;
        float w3 = exp2f(v3 * a3); ac3 += w3 * xv.w; dn3 += w3;
    }
    if (g == 0) {
        float r = ac0 / (dn0 + 1e-16f) + ac1 / (dn1 + 1e-16f)
                + ac2 / (dn2 + 1e-16f) + ac3 / (dn3 + 1e-16f);
        out[node] = r * 0.25f;
    }
}

// ======================= FALLBACK PATH (round-4 kernels) ===================

__global__ __launch_bounds__(256) void k_permute_fb(const int* __restrict__ csr,
                                                    const float* __restrict__ ea,
                                                    const float* __restrict__ We2,
                                                    float* __restrict__ ea_all,
                                                    float* __restrict__ qe_all, int E) {
    __shared__ float sW[64];
    int t = threadIdx.x;
    if (t < 64) sW[t] = We2[t];
    __syncthreads();
    int j = blockIdx.x * 256 + t;
    if (j >= E) return;
    int e = csr[j];
    const float4* s4 = (const float4*)(ea + (size_t)e * 16);
    float4* d4 = (float4*)(ea_all + (size_t)j * 16);
    float q0 = 0.f, q1 = 0.f, q2 = 0.f, q3 = 0.f;
    #pragma unroll
    for (int b = 0; b < 4; ++b) {
        float4 v = s4[b];
        d4[b] = v;
        int k = 4 * b;
        q0 += v.x * sW[k*4+0] + v.y * sW[(k+1)*4+0] + v.z * sW[(k+2)*4+0] + v.w * sW[(k+3)*4+0];
        q1 += v.x * sW[k*4+1] + v.y * sW[(k+1)*4+1] + v.z * sW[(k+2)*4+1] + v.w * sW[(k+3)*4+1];
        q2 += v.x * sW[k*4+2] + v.y * sW[(k+1)*4+2] + v.z * sW[(k+2)*4+2] + v.w * sW[(k+3)*4+2];
        q3 += v.x * sW[k*4+3] + v.y * sW[(k+1)*4+3] + v.z * sW[(k+2)*4+3] + v.w * sW[(k+3)*4+3];
    }
    *(float4*)(qe_all + (size_t)j * 4) = make_float4(q0, q1, q2, q3);
}

__global__ __launch_bounds__(256) void k_loopq_fb(float* __restrict__ ea_all,
                                                  float* __restrict__ qe_all,
                                                  const int* __restrict__ rowptr,
                                                  int E, int N) {
    int idx = blockIdx.x * 256 + threadIdx.x;
    int tot1 = N * 16;
    if (idx < tot1) {
        int n = idx >> 4, k = idx & 15;
        int rs = rowptr[n], re = rowptr[n + 1];
        float s = 0.f;
        for (int j = rs; j < re; ++j) s += ea_all[(size_t)j * 16 + k];
        int dg = re - rs;
        ea_all[(size_t)(E + n) * 16 + k] = s / (float)(dg > 1 ? dg : 1);
    } else if (idx < tot1 + N * 4) {
        int i2 = idx - tot1;
        int n = i2 >> 2, c = i2 & 3;
        int rs = rowptr[n], re = rowptr[n + 1];
        float s = 0.f;
        for (int j = rs; j < re; ++j) s += qe_all[(size_t)j * 4 + c];
        int dg = re - rs;
        qe_all[(size_t)(E + n) * 4 + c] = s / (float)(dg > 1 ? dg : 1);
    }
}

__global__ __launch_bounds__(256) void k_fused1_fb(
    const int* __restrict__ src, const int* __restrict__ rowptr, const int* __restrict__ csr,
    const ushort* __restrict__ xl_bf, const float* __restrict__ xr,
    const float* __restrict__ ea_all,
    const float* __restrict__ We, const float* __restrict__ att,
    const float* __restrict__ Wl2, const float* __restrict__ Wr2,
    float* __restrict__ xl2, float* __restrict__ xr2, int E, int N) {
    int t = threadIdx.x;
    int l = t & 63;
    int n = (blockIdx.x * 256 + t) >> 6;
    if (n >= N) return;
    float2 we[16];
    #pragma unroll
    for (int k = 0; k < 16; ++k) we[k] = *(const float2*)(We + k * 128 + 2 * l);
    float2 av  = *(const float2*)(att + 2 * l);
    float2 xrv = *(const float2*)(xr + (size_t)n * 128 + 2 * l);
    int rs = rowptr[n], re = rowptr[n + 1];
    int deg = re - rs;
    int nslots = deg + 1;
    int srcv = n;
    if (l < deg) srcv = src[csr[rs + l]];
    float acc0 = 0.f, acc1 = 0.f, den = 0.f;
    for (int base = 0; base < nslots; base += 4) {
        int sA[4], rowA[4];
        float mask[4];
        #pragma unroll
        for (int c = 0; c < 4; ++c) {
            int slot = base + c;
            bool valid = slot < nslots;
            mask[c] = valid ? 1.f : 0.f;
            int eff = valid ? slot : deg;
            int s, row;
            if (eff < deg) {
                s = (eff < 64) ? __shfl(srcv, eff) : src[csr[rs + eff]];
                row = rs + eff;
            } else { s = n; row = E + n; }
            sA[c] = s; rowA[c] = row;
        }
        unsigned xw[4];
        #pragma unroll
        for (int c = 0; c < 4; ++c)
            xw[c] = *(const unsigned*)(xl_bf + (size_t)sA[c] * 128 + 2 * l);
        float4 eav[4][4];
        #pragma unroll
        for (int c = 0; c < 4; ++c) {
            const float4* p = (const float4*)(ea_all + (size_t)rowA[c] * 16);
            eav[c][0] = p[0]; eav[c][1] = p[1]; eav[c][2] = p[2]; eav[c][3] = p[3];
        }
        #pragma unroll
        for (int c = 0; c < 4; ++c) {
            const float* a = (const float*)&eav[c][0];
            float vx = xrv.x, vy = xrv.y;
            #pragma unroll
            for (int k = 0; k < 16; ++k) { vx += a[k] * we[k].x; vy += a[k] * we[k].y; }
            float xl0 = __uint_as_float(xw[c] << 16);
            float xl1 = __uint_as_float(xw[c] & 0xffff0000u);
            vx += xl0; vy += xl1;
            vx = fmaxf(vx, 0.2f * vx);
            vy = fmaxf(vy, 0.2f * vy);
            float p = row_sum16(av.x * vx + av.y * vy);
            float w = __expf(p) * mask[c];
            acc0 += w * xl0; acc1 += w * xl1; den += w;
        }
    }
    float rdn = 1.f / (den + 1e-16f);
    float h0 = acc0 * rdn, h1 = acc1 * rdn;
    h0 = h0 > 0.f ? h0 : 0.01f * h0;
    h1 = h1 > 0.f ? h1 : 0.01f * h1;
    float4 wla = *(const float4*)(Wl2 + (size_t)(2 * l) * 4);
    float4 wlb = *(const float4*)(Wl2 + (size_t)(2 * l + 1) * 4);
    float4 wra = *(const float4*)(Wr2 + (size_t)(2 * l) * 4);
    float4 wrb = *(const float4*)(Wr2 + (size_t)(2 * l + 1) * 4);
    float q0 = red64(h0 * wla.x + h1 * wlb.x);
    float q1 = red64(h0 * wla.y + h1 * wlb.y);
    float q2 = red64(h0 * wla.z + h1 * wlb.z);
    float q3 = red64(h0 * wla.w + h1 * wlb.w);
    float q4 = red64(h0 * wra.x + h1 * wrb.x);
    float q5 = red64(h0 * wra.y + h1 * wrb.y);
    float q6 = red64(h0 * wra.z + h1 * wrb.z);
    float q7 = red64(h0 * wra.w + h1 * wrb.w);
    if (l == 0) {
        *(float4*)(xl2 + (size_t)n * 4) = make_float4(q0, q1, q2, q3);
        *(float4*)(xr2 + (size_t)n * 4) = make_float4(q4, q5, q6, q7);
    }
}

__global__ __launch_bounds__(256) void k_fused2_fb(
    const int* __restrict__ src, const int* __restrict__ rowptr, const int* __restrict__ csr,
    const float* __restrict__ xl2, const float* __restrict__ xr2,
    const float* __restrict__ qe_all,
    const float* __restrict__ att2, float* __restrict__ out, int E, int N) {
    int t = threadIdx.x;
    int l = t & 63;
    int g = l & 15;
    int node = (((blockIdx.x * 256 + t) >> 6) << 2) + (l >> 4);
    if (node >= N) return;
    int rs = rowptr[node], re = rowptr[node + 1];
    int deg = re - rs;
    float4 xrv = *(const float4*)(xr2 + (size_t)node * 4);
    float a0 = att2[0], a1 = att2[1], a2 = att2[2], a3 = att2[3];
    float ac0 = 0.f, ac1 = 0.f, ac2 = 0.f, ac3 = 0.f;
    float dn0 = 0.f, dn1 = 0.f, dn2 = 0.f, dn3 = 0.f;
    for (int slot = g; slot <= deg; slot += 16) {
        int s, row;
        if (slot < deg) { row = rs + slot; s = src[csr[row]]; }
        else            { row = E + node;  s = node; }
        float4 q = *(const float4*)(qe_all + (size_t)row * 4);
        float4 xv = *(const float4*)(xl2 + (size_t)s * 4);
        float v0 = xv.x + xrv.x + q.x; v0 = fmaxf(v0, 0.2f * v0);
        float v1 = xv.y + xrv.y + q.y; v1 = fmaxf(v1, 0.2f * v1);
        float v2 = xv.z + xrv.z + q.z; v2 = fmaxf(v2, 0.2f * v2);
        float v3 = xv.w + xrv.w + q.w; v3 = fmaxf(v3, 0.2f * v3);
        float w0 = __expf(v0 * a0); ac0 += w0 * xv.x; dn0 += w0;
        float w1 = __expf(v1 * a1); ac1 += w1 * xv.y; dn1 += w1;
        float w2 = __expf(v2 * a2); ac2 += w2 * xv.z; dn2 += w2;
        float w3 = __expf(v3 * a3); ac3 += w3 * xv.w; dn3 += w3;
    }
    ac0 = row_sum16(ac0); ac1 = row_sum16(ac1);
    ac2 = row_sum16(ac2); ac3 = row_sum16(ac3);
    dn0 = row_sum16(dn0); dn1 = row_sum16(dn1);
    dn2 = row_sum16(dn2); dn3 = row_sum16(dn3);
    if (g == 0) {
        float r = ac0 / (dn0 + 1e-16f) + ac1 / (dn1 + 1e-16f)
                + ac2 / (dn2 + 1e-16f) + ac3 / (dn3 + 1e-16f);
        out[node] = r * 0.25f;
    }
}

// ===========================================================================

extern "C" void kernel_launch(void* const* d_in, const int* in_sizes, int n_in,
                              void* d_out, int out_size, void* d_ws, size_t ws_size,
                              hipStream_t stream) {
    const float* x         = (const float*)d_in[0];
    const int*   edge_index= (const int*)d_in[1];
    const float* edge_attr = (const float*)d_in[2];
    const float* Wl1       = (const float*)d_in[3];
    const float* Wr1       = (const float*)d_in[4];
    const float* We1       = (const float*)d_in[5];
    const float* att1      = (const float*)d_in[6];
    const float* Wl2       = (const float*)d_in[7];
    const float* Wr2       = (const float*)d_in[8];
    const float* We2       = (const float*)d_in[9];
    const float* att2      = (const float*)d_in[10];
    float* outp = (float*)d_out;

    const int F = 128, HC = 128, EDIM = 16;
    int N = in_sizes[0] / F;
    int E = in_sizes[1] / 2;
    const int* src = edge_index;
    const int* dst = edge_index + E;

    char* ws = (char*)d_ws;
    size_t off = 0;
    auto alloc = [&](size_t bytes) {
        char* p = ws + off;
        off += (bytes + 255) & ~(size_t)255;
        return p;
    };
    // shared prefix
    int*    deg    = (int*)alloc((size_t)N * 4);
    int*    cursor = (int*)alloc((size_t)N * 4);
    int*    rowptr = (int*)alloc((size_t)(N + 1) * 4);
    int*    part   = (int*)alloc(((size_t)N / 1024 + 2) * 4);
    int*    csr    = (int*)alloc((size_t)E * 4);
    ushort* xl_bf  = (ushort*)alloc((size_t)N * HC * 2);
    float*  xr1    = (float*)alloc((size_t)N * HC * 4);
    float*  xl2    = (float*)alloc((size_t)N * 4 * 4);
    float*  xr2    = (float*)alloc((size_t)N * 4 * 4);
    size_t shared_off = off;

    // new-path extras
    int*      src_perm = (int*)alloc((size_t)E * 4);
    float*    qe2      = (float*)alloc((size_t)E * 4 * 4);
    unsigned* qe1      = (unsigned*)alloc((size_t)E * 64 * 4);
    size_t need_new = off;

    int eb = (E + 255) / 256;
    int nb = (N + 1023) / 1024;

    hipMemsetAsync(deg, 0, (size_t)((char*)rowptr - (char*)deg), stream);
    k_count_deg<<<eb, 256, 0, stream>>>(dst, deg, E);
    k_scan1<<<nb, 1024, 0, stream>>>(deg, rowptr, part, N);
    k_scan2<<<1, 64, 0, stream>>>(part, nb);
    k_scan3<<<(N + 255) / 256, 256, 0, stream>>>(rowptr, part, N, E);
    k_scatter<<<eb, 256, 0, stream>>>(dst, rowptr, cursor, csr, E);
    k_gemm1<<<(N + 31) / 32, 256, 0, stream>>>(x, Wl1, Wr1, xl_bf, xr1, N);

    if (need_new <= ws_size) {
        k_edge<<<(E * 64 + 255) / 256, 256, 0, stream>>>(csr, src, edge_attr, We1, We2,
                                                         qe1, qe2, src_perm, E);
        k_fused1_q<<<(N + 3) / 4, 256, 0, stream>>>(rowptr, src_perm, xl_bf, xr1, qe1,
                                                    att1, Wl2, Wr2, xl2, xr2, N);
        k_fused2_q<<<(N + 15) / 16, 256, 0, stream>>>(rowptr, src_perm, xl2, xr2, qe2,
                                                      att2, outp, N);
    } else {
        // fallback: round-4 layout in place of new-path extras
        off = shared_off;
        float* ea_all = (float*)alloc((size_t)(E + N) * EDIM * 4);
        float* qe_all = (float*)alloc((size_t)(E + N) * 4 * 4);
        k_permute_fb<<<eb, 256, 0, stream>>>(csr, edge_attr, We2, ea_all, qe_all, E);
        k_loopq_fb<<<(N * 20 + 255) / 256, 256, 0, stream>>>(ea_all, qe_all, rowptr, E, N);
        k_fused1_fb<<<(N + 3) / 4, 256, 0, stream>>>(src, rowptr, csr, xl_bf, xr1, ea_all,
                                                     We1, att1, Wl2, Wr2, xl2, xr2, E, N);
        k_fused2_fb<<<(N + 15) / 16, 256, 0, stream>>>(src, rowptr, csr, xl2, xr2, qe_all,
                                                       att2, outp, E, N);
    }
}

// Round 6
// 450.232 us; speedup vs baseline: 1.9875x; 1.9875x over previous
//
#include <hip/hip_runtime.h>
#include <math.h>

// ---------------------------------------------------------------------------
// GATv2 x2 on MI355X.
// Path:
//   memset -> count_deg -> scan1/2/3 -> scatter(CSR) -> gemm1(xl bf16, xr f32)
//   -> k_edge (persistent waves: qe1=ea@We1 bf16 CSR-order, qe2=ea@We2, src_perm)
//   -> k_fused1_q (softmax+aggregate+lrelu+gemv2; self-term = in-loop qe1 mean)
//   -> k_fused2_q (softmax+aggregate+head-mean;   self-term = in-loop qe2 mean)
// ---------------------------------------------------------------------------

static __device__ __forceinline__ ushort f2bf(float f) {
    unsigned u = __float_as_uint(f);
    unsigned r = (u + 0x7fffu + ((u >> 16) & 1u)) >> 16;  // RNE
    return (ushort)r;
}

// sum across each 16-lane row via DPP row_ror (pure VALU, no DS)
static __device__ __forceinline__ float row_sum16(float x) {
    x += __int_as_float(__builtin_amdgcn_update_dpp(0, __float_as_int(x), 0x121, 0xf, 0xf, true));
    x += __int_as_float(__builtin_amdgcn_update_dpp(0, __float_as_int(x), 0x122, 0xf, 0xf, true));
    x += __int_as_float(__builtin_amdgcn_update_dpp(0, __float_as_int(x), 0x124, 0xf, 0xf, true));
    x += __int_as_float(__builtin_amdgcn_update_dpp(0, __float_as_int(x), 0x128, 0xf, 0xf, true));
    return x;
}

static __device__ __forceinline__ float red64(float x) {  // 64-lane sum
    x = row_sum16(x);
    x += __shfl_xor(x, 16);
    x += __shfl_xor(x, 32);
    return x;
}

__global__ void k_count_deg(const int* __restrict__ dst, int* __restrict__ deg, int E) {
    int i = blockIdx.x * blockDim.x + threadIdx.x;
    if (i < E) atomicAdd(&deg[dst[i]], 1);
}

__global__ __launch_bounds__(1024) void k_scan1(const int* __restrict__ deg,
                                                int* __restrict__ rowptr,
                                                int* __restrict__ part, int N) {
    __shared__ int wsum[16];
    int t = threadIdx.x, l = t & 63, w = t >> 6;
    int i = blockIdx.x * 1024 + t;
    int v = (i < N) ? deg[i] : 0;
    int sc = v;
    #pragma unroll
    for (int off = 1; off < 64; off <<= 1) {
        int y = __shfl_up(sc, off);
        if (l >= off) sc += y;
    }
    if (l == 63) wsum[w] = sc;
    __syncthreads();
    if (w == 0) {
        int pv = (l < 16) ? wsum[l] : 0;
        int psc = pv;
        #pragma unroll
        for (int off = 1; off < 16; off <<= 1) {
            int y = __shfl_up(psc, off);
            if (l >= off) psc += y;
        }
        if (l < 16) wsum[l] = psc - pv;
    }
    __syncthreads();
    if (i < N) rowptr[i] = wsum[w] + sc - v;
    if (t == 1023) part[blockIdx.x] = wsum[15] + sc;
}

__global__ void k_scan2(int* __restrict__ part, int nb) {
    int l = threadIdx.x & 63;
    int run = 0;
    for (int base = 0; base < nb; base += 64) {
        int i = base + l;
        int v = (i < nb) ? part[i] : 0;
        int sc = v;
        #pragma unroll
        for (int off = 1; off < 64; off <<= 1) {
            int y = __shfl_up(sc, off);
            if (l >= off) sc += y;
        }
        if (i < nb) part[i] = run + sc - v;
        run += __shfl(sc, 63);
    }
}

__global__ void k_scan3(int* __restrict__ rowptr, const int* __restrict__ part, int N, int E) {
    int i = blockIdx.x * 256 + threadIdx.x;
    if (i < N) rowptr[i] += part[i >> 10];
    if (i == 0) rowptr[N] = E;
}

__global__ void k_scatter(const int* __restrict__ dst, const int* __restrict__ rowptr,
                          int* __restrict__ cursor, int* __restrict__ csr, int E) {
    int i = blockIdx.x * blockDim.x + threadIdx.x;
    if (i < E) {
        int d = dst[i];
        int pos = rowptr[d] + atomicAdd(&cursor[d], 1);
        csr[pos] = i;
    }
}

// xl1 = x @ Wl1 (bf16 out), xr1 = x @ Wr1 (f32 out)
__global__ __launch_bounds__(256) void k_gemm1(const float* __restrict__ x,
                                               const float* __restrict__ Wl,
                                               const float* __restrict__ Wr,
                                               ushort* __restrict__ xl, float* __restrict__ xr,
                                               int N) {
    __shared__ float xs[32 * 128];
    int r0 = blockIdx.x * 32;
    int t = threadIdx.x;
    for (int i = t * 4; i < 32 * 128; i += 256 * 4) {
        int r = i >> 7;
        float4 v = make_float4(0.f, 0.f, 0.f, 0.f);
        if (r0 + r < N) v = *(const float4*)(&x[(size_t)(r0 + r) * 128 + (i & 127)]);
        *(float4*)(&xs[i]) = v;
    }
    __syncthreads();
    int c = t & 127;
    int rbase = (t >> 7) * 16;
    float accl[16], accr[16];
    #pragma unroll
    for (int r = 0; r < 16; ++r) { accl[r] = 0.f; accr[r] = 0.f; }
    for (int k = 0; k < 128; ++k) {
        float wl = Wl[k * 128 + c];
        float wr = Wr[k * 128 + c];
        #pragma unroll
        for (int r = 0; r < 16; ++r) {
            float xv = xs[(rbase + r) * 128 + k];
            accl[r] += xv * wl;
            accr[r] += xv * wr;
        }
    }
    #pragma unroll
    for (int r = 0; r < 16; ++r) {
        int row = r0 + rbase + r;
        if (row < N) {
            xl[(size_t)row * 128 + c] = f2bf(accl[r]);
            xr[(size_t)row * 128 + c] = accr[r];
        }
    }
}

// persistent-wave edge kernel: qe1[j] = ea[csr[j]]@We1 (bf16 x128),
// qe2[j] = ea@We2 (f32 x4), src_perm[j] = src[csr[j]].
// We1 columns (2l,2l+1) and We2 column (l&3) live in registers for the
// whole kernel; ea rows arrive via wave-uniform (scalar) loads.
__global__ __launch_bounds__(256) void k_edge(
    const int* __restrict__ csr, const int* __restrict__ src,
    const float* __restrict__ ea, const float* __restrict__ We1,
    const float* __restrict__ We2,
    unsigned* __restrict__ qe1, float* __restrict__ qe2,
    int* __restrict__ src_perm, int E, int nwaves) {
    int t = threadIdx.x, l = t & 63;
    int gw = (blockIdx.x * 256 + t) >> 6;
    float2 we[16];
    #pragma unroll
    for (int k = 0; k < 16; ++k) we[k] = *(const float2*)(We1 + k * 128 + 2 * l);
    float w2[16];
    #pragma unroll
    for (int k = 0; k < 16; ++k) w2[k] = We2[k * 4 + (l & 3)];
    int stride = nwaves * 4;
    for (int base = gw * 4; base < E; base += stride) {
        int jj[4], ee[4];
        #pragma unroll
        for (int c = 0; c < 4; ++c) {
            int j = base + c;
            jj[c] = (j < E) ? j : E - 1;   // clamped dup -> identical rewrite, benign
            ee[c] = __builtin_amdgcn_readfirstlane(csr[jj[c]]);
        }
        int sp[4];
        #pragma unroll
        for (int c = 0; c < 4; ++c) sp[c] = src[ee[c]];
        float4 rows[4][4];
        #pragma unroll
        for (int c = 0; c < 4; ++c) {
            const float4* p4 = (const float4*)(ea + (size_t)ee[c] * 16);
            rows[c][0] = p4[0]; rows[c][1] = p4[1];
            rows[c][2] = p4[2]; rows[c][3] = p4[3];
        }
        #pragma unroll
        for (int c = 0; c < 4; ++c) {
            const float* a = (const float*)&rows[c][0];
            float vx = 0.f, vy = 0.f, q = 0.f;
            #pragma unroll
            for (int k = 0; k < 16; ++k) {
                vx += a[k] * we[k].x;
                vy += a[k] * we[k].y;
                q  += a[k] * w2[k];
            }
            qe1[(size_t)jj[c] * 64 + l] = (unsigned)f2bf(vx) | ((unsigned)f2bf(vy) << 16);
            if (l == 0) src_perm[jj[c]] = sp[c];
            if (l < 4) qe2[(size_t)jj[c] * 4 + l] = q;
        }
    }
}

// layer 1 fused (wave per node, lane l owns channels 2l,2l+1), unroll-4,
// self-loop term = running mean of qe1 over incoming edges.
__global__ __launch_bounds__(256) void k_fused1_q(
    const int* __restrict__ rowptr, const int* __restrict__ src_perm,
    const ushort* __restrict__ xl_bf, const float* __restrict__ xr,
    const unsigned* __restrict__ qe1, const float* __restrict__ att,
    const float* __restrict__ Wl2, const float* __restrict__ Wr2,
    float* __restrict__ xl2, float* __restrict__ xr2, int N) {
    int t = threadIdx.x, l = t & 63;
    int n = (blockIdx.x * 256 + t) >> 6;
    if (n >= N) return;
    const float RLN2 = 1.44269504f;
    float2 av = *(const float2*)(att + 2 * l);
    av.x *= RLN2; av.y *= RLN2;
    float2 xrv = *(const float2*)(xr + (size_t)n * 128 + 2 * l);
    int rs = rowptr[n], re = rowptr[n + 1];
    int deg = re - rs;
    float acc0 = 0.f, acc1 = 0.f, den = 0.f, mq0 = 0.f, mq1 = 0.f;
    for (int base = 0; base < deg; base += 4) {
        int rowA[4];
        float mask[4];
        #pragma unroll
        for (int c = 0; c < 4; ++c) {
            int slot = base + c;
            bool valid = slot < deg;
            mask[c] = valid ? 1.f : 0.f;
            rowA[c] = valid ? rs + slot : rs;
        }
        int sA[4];
        #pragma unroll
        for (int c = 0; c < 4; ++c) sA[c] = src_perm[rowA[c]];
        unsigned qw[4];
        #pragma unroll
        for (int c = 0; c < 4; ++c) qw[c] = qe1[(size_t)rowA[c] * 64 + l];
        unsigned xw[4];
        #pragma unroll
        for (int c = 0; c < 4; ++c)
            xw[c] = *(const unsigned*)(xl_bf + (size_t)sA[c] * 128 + 2 * l);
        #pragma unroll
        for (int c = 0; c < 4; ++c) {
            float q0 = __uint_as_float(qw[c] << 16);
            float q1 = __uint_as_float(qw[c] & 0xffff0000u);
            float xl0 = __uint_as_float(xw[c] << 16);
            float xl1 = __uint_as_float(xw[c] & 0xffff0000u);
            float vx = xrv.x + xl0 + q0;
            float vy = xrv.y + xl1 + q1;
            vx = fmaxf(vx, 0.2f * vx);
            vy = fmaxf(vy, 0.2f * vy);
            float p = row_sum16(av.x * vx + av.y * vy);
            float w = exp2f(p) * mask[c];
            acc0 += w * xl0;
            acc1 += w * xl1;
            den += w;
            mq0 += mask[c] * q0;
            mq1 += mask[c] * q1;
        }
    }
    {   // self loop: qe_self = mean of incoming qe1
        float inv = 1.f / (float)(deg > 1 ? deg : 1);
        float q0 = mq0 * inv, q1 = mq1 * inv;
        unsigned xw = *(const unsigned*)(xl_bf + (size_t)n * 128 + 2 * l);
        float xl0 = __uint_as_float(xw << 16);
        float xl1 = __uint_as_float(xw & 0xffff0000u);
        float vx = xrv.x + xl0 + q0;
        float vy = xrv.y + xl1 + q1;
        vx = fmaxf(vx, 0.2f * vx);
        vy = fmaxf(vy, 0.2f * vy);
        float p = row_sum16(av.x * vx + av.y * vy);
        float w = exp2f(p);
        acc0 += w * xl0;
        acc1 += w * xl1;
        den += w;
    }
    float rdn = 1.f / (den + 1e-16f);
    float h0 = acc0 * rdn, h1 = acc1 * rdn;
    h0 = h0 > 0.f ? h0 : 0.01f * h0;
    h1 = h1 > 0.f ? h1 : 0.01f * h1;
    float4 wla = *(const float4*)(Wl2 + (size_t)(2 * l) * 4);
    float4 wlb = *(const float4*)(Wl2 + (size_t)(2 * l + 1) * 4);
    float4 wra = *(const float4*)(Wr2 + (size_t)(2 * l) * 4);
    float4 wrb = *(const float4*)(Wr2 + (size_t)(2 * l + 1) * 4);
    float q0 = red64(h0 * wla.x + h1 * wlb.x);
    float q1 = red64(h0 * wla.y + h1 * wlb.y);
    float q2 = red64(h0 * wla.z + h1 * wlb.z);
    float q3 = red64(h0 * wla.w + h1 * wlb.w);
    float q4 = red64(h0 * wra.x + h1 * wrb.x);
    float q5 = red64(h0 * wra.y + h1 * wrb.y);
    float q6 = red64(h0 * wra.z + h1 * wrb.z);
    float q7 = red64(h0 * wra.w + h1 * wrb.w);
    if (l == 0) {
        *(float4*)(xl2 + (size_t)n * 4) = make_float4(q0, q1, q2, q3);
        *(float4*)(xr2 + (size_t)n * 4) = make_float4(q4, q5, q6, q7);
    }
}

// layer 2 fused: 16 lanes per node, self-term = in-loop mean of qe2
__global__ __launch_bounds__(256) void k_fused2_q(
    const int* __restrict__ rowptr, const int* __restrict__ src_perm,
    const float* __restrict__ xl2, const float* __restrict__ xr2,
    const float* __restrict__ qe2, const float* __restrict__ att2,
    float* __restrict__ out, int N) {
    int t = threadIdx.x, l = t & 63, g = l & 15;
    int node = (((blockIdx.x * 256 + t) >> 6) << 2) + (l >> 4);
    if (node >= N) return;
    int rs = rowptr[node], re = rowptr[node + 1];
    int deg = re - rs;
    float4 xrv = *(const float4*)(xr2 + (size_t)node * 4);
    const float RLN2 = 1.44269504f;
    float a0 = att2[0] * RLN2, a1 = att2[1] * RLN2;
    float a2 = att2[2] * RLN2, a3 = att2[3] * RLN2;
    float ac0 = 0.f, ac1 = 0.f, ac2 = 0.f, ac3 = 0.f;
    float dn0 = 0.f, dn1 = 0.f, dn2 = 0.f, dn3 = 0.f;
    float mq0 = 0.f, mq1 = 0.f, mq2 = 0.f, mq3 = 0.f;
    for (int slot = g; slot < deg; slot += 16) {
        int row = rs + slot;
        int s = src_perm[row];
        float4 q = *(const float4*)(qe2 + (size_t)row * 4);
        float4 xv = *(const float4*)(xl2 + (size_t)s * 4);
        float v0 = xv.x + xrv.x + q.x; v0 = fmaxf(v0, 0.2f * v0);
        float v1 = xv.y + xrv.y + q.y; v1 = fmaxf(v1, 0.2f * v1);
        float v2 = xv.z + xrv.z + q.z; v2 = fmaxf(v2, 0.2f * v2);
        float v3 = xv.w + xrv.w + q.w; v3 = fmaxf(v3, 0.2f * v3);
        float w0 = exp2f(v0 * a0); ac0 += w0 * xv.x; dn0 += w0;
        float w1 = exp2f(v1 * a1); ac1 += w1 * xv.y; dn1 += w1;
        float w2 = exp2f(v2 * a2); ac2 += w2 * xv.z; dn2 += w2;
        float w3 = exp2f(v3 * a3); ac3 += w3 * xv.w; dn3 += w3;
        mq0 += q.x; mq1 += q.y; mq2 += q.z; mq3 += q.w;
    }
    ac0 = row_sum16(ac0); ac1 = row_sum16(ac1);
    ac2 = row_sum16(ac2); ac3 = row_sum16(ac3);
    dn0 = row_sum16(dn0); dn1 = row_sum16(dn1);
    dn2 = row_sum16(dn2); dn3 = row_sum16(dn3);
    mq0 = row_sum16(mq0); mq1 = row_sum16(mq1);
    mq2 = row_sum16(mq2); mq3 = row_sum16(mq3);
    {   // self loop (uniform across the 16-lane group)
        float inv = 1.f / (float)(deg > 1 ? deg : 1);
        float4 xv = *(const float4*)(xl2 + (size_t)node * 4);
        float v0 = xv.x + xrv.x + mq0 * inv; v0 = fmaxf(v0, 0.2f * v0);
        float v1 = xv.y + xrv.y + mq1 * inv; v1 = fmaxf(v1, 0.2f * v1);
        float v2 = xv.z + xrv.z + mq2 * inv; v2 = fmaxf(v2, 0.2f * v2);
        float v3 = xv.w + xrv.w + mq3 * inv; v3 = fmaxf(v3, 0.2f * v3);
        float w0 = exp2f(v0 * a0); ac0 += w0 * xv.x; dn0 += w0;
        float w1 = exp2f(v1 * a1); ac1 += w1 * xv.y; dn1 += w1;
        float w2 = exp2f(v2 * a2); ac2 += w2 * xv.z; dn2 += w2;
        float w3 = exp2f(v3 * a3); ac3 += w3 * xv.w; dn3 += w3;
    }
    if (g == 0) {
        float r = ac0 / (dn0 + 1e-16f) + ac1 / (dn1 + 1e-16f)
                + ac2 / (dn2 + 1e-16f) + ac3 / (dn3 + 1e-16f);
        out[node] = r * 0.25f;
    }
}

extern "C" void kernel_launch(void* const* d_in, const int* in_sizes, int n_in,
                              void* d_out, int out_size, void* d_ws, size_t ws_size,
                              hipStream_t stream) {
    const float* x         = (const float*)d_in[0];
    const int*   edge_index= (const int*)d_in[1];
    const float* edge_attr = (const float*)d_in[2];
    const float* Wl1       = (const float*)d_in[3];
    const float* Wr1       = (const float*)d_in[4];
    const float* We1       = (const float*)d_in[5];
    const float* att1      = (const float*)d_in[6];
    const float* Wl2       = (const float*)d_in[7];
    const float* Wr2       = (const float*)d_in[8];
    const float* We2       = (const float*)d_in[9];
    const float* att2      = (const float*)d_in[10];
    float* outp = (float*)d_out;

    const int F = 128, HC = 128;
    int N = in_sizes[0] / F;
    int E = in_sizes[1] / 2;
    const int* src = edge_index;
    const int* dst = edge_index + E;

    char* ws = (char*)d_ws;
    size_t off = 0;
    auto alloc = [&](size_t bytes) {
        char* p = ws + off;
        off += (bytes + 255) & ~(size_t)255;
        return p;
    };
    int*      deg      = (int*)alloc((size_t)N * 4);
    int*      cursor   = (int*)alloc((size_t)N * 4);
    int*      rowptr   = (int*)alloc((size_t)(N + 1) * 4);
    int*      part     = (int*)alloc(((size_t)N / 1024 + 2) * 4);
    int*      csr      = (int*)alloc((size_t)E * 4);
    ushort*   xl_bf    = (ushort*)alloc((size_t)N * HC * 2);
    float*    xr1      = (float*)alloc((size_t)N * HC * 4);
    float*    xl2      = (float*)alloc((size_t)N * 4 * 4);
    float*    xr2      = (float*)alloc((size_t)N * 4 * 4);
    int*      src_perm = (int*)alloc((size_t)E * 4);
    float*    qe2      = (float*)alloc((size_t)E * 4 * 4);
    unsigned* qe1      = (unsigned*)alloc((size_t)E * 64 * 4);

    int eb = (E + 255) / 256;
    int nb = (N + 1023) / 1024;

    hipMemsetAsync(deg, 0, (size_t)((char*)rowptr - (char*)deg), stream);
    k_count_deg<<<eb, 256, 0, stream>>>(dst, deg, E);
    k_scan1<<<nb, 1024, 0, stream>>>(deg, rowptr, part, N);
    k_scan2<<<1, 64, 0, stream>>>(part, nb);
    k_scan3<<<(N + 255) / 256, 256, 0, stream>>>(rowptr, part, N, E);
    k_scatter<<<eb, 256, 0, stream>>>(dst, rowptr, cursor, csr, E);
    k_gemm1<<<(N + 31) / 32, 256, 0, stream>>>(x, Wl1, Wr1, xl_bf, xr1, N);
    const int EDGE_BLOCKS = 2048;
    k_edge<<<EDGE_BLOCKS, 256, 0, stream>>>(csr, src, edge_attr, We1, We2,
                                            qe1, qe2, src_perm, E, EDGE_BLOCKS * 4);
    k_fused1_q<<<(N + 3) / 4, 256, 0, stream>>>(rowptr, src_perm, xl_bf, xr1, qe1,
                                                att1, Wl2, Wr2, xl2, xr2, N);
    k_fused2_q<<<(N + 15) / 16, 256, 0, stream>>>(rowptr, src_perm, xl2, xr2, qe2,
                                                  att2, outp, N);
}

// Round 7
// 398.117 us; speedup vs baseline: 2.2476x; 1.1309x over previous
//
#include <hip/hip_runtime.h>
#include <math.h>

// ---------------------------------------------------------------------------
// GATv2 x2 on MI355X.
// Path:
//   memset -> count_deg -> scan1/2/3 -> scatter(CSR) -> gemm1(xl bf16, xr f32)
//   -> k_edge (LDS-staged 64-edge tiles: qe1=ea@We1 bf16 CSR-order, qe2, src_perm)
//   -> k_fused1_q (softmax+aggregate+lrelu+gemv2; self-term = in-loop qe1 mean)
//   -> k_fused2_q (softmax+aggregate+head-mean;   self-term = in-loop qe2 mean)
// ---------------------------------------------------------------------------

static __device__ __forceinline__ ushort f2bf(float f) {
    unsigned u = __float_as_uint(f);
    unsigned r = (u + 0x7fffu + ((u >> 16) & 1u)) >> 16;  // RNE
    return (ushort)r;
}

// sum across each 16-lane row via DPP row_ror (pure VALU, no DS)
static __device__ __forceinline__ float row_sum16(float x) {
    x += __int_as_float(__builtin_amdgcn_update_dpp(0, __float_as_int(x), 0x121, 0xf, 0xf, true));
    x += __int_as_float(__builtin_amdgcn_update_dpp(0, __float_as_int(x), 0x122, 0xf, 0xf, true));
    x += __int_as_float(__builtin_amdgcn_update_dpp(0, __float_as_int(x), 0x124, 0xf, 0xf, true));
    x += __int_as_float(__builtin_amdgcn_update_dpp(0, __float_as_int(x), 0x128, 0xf, 0xf, true));
    return x;
}

static __device__ __forceinline__ float red64(float x) {  // 64-lane sum
    x = row_sum16(x);
    x += __shfl_xor(x, 16);
    x += __shfl_xor(x, 32);
    return x;
}

__global__ void k_count_deg(const int* __restrict__ dst, int* __restrict__ deg, int E) {
    int i = blockIdx.x * blockDim.x + threadIdx.x;
    if (i < E) atomicAdd(&deg[dst[i]], 1);
}

__global__ __launch_bounds__(1024) void k_scan1(const int* __restrict__ deg,
                                                int* __restrict__ rowptr,
                                                int* __restrict__ part, int N) {
    __shared__ int wsum[16];
    int t = threadIdx.x, l = t & 63, w = t >> 6;
    int i = blockIdx.x * 1024 + t;
    int v = (i < N) ? deg[i] : 0;
    int sc = v;
    #pragma unroll
    for (int off = 1; off < 64; off <<= 1) {
        int y = __shfl_up(sc, off);
        if (l >= off) sc += y;
    }
    if (l == 63) wsum[w] = sc;
    __syncthreads();
    if (w == 0) {
        int pv = (l < 16) ? wsum[l] : 0;
        int psc = pv;
        #pragma unroll
        for (int off = 1; off < 16; off <<= 1) {
            int y = __shfl_up(psc, off);
            if (l >= off) psc += y;
        }
        if (l < 16) wsum[l] = psc - pv;
    }
    __syncthreads();
    if (i < N) rowptr[i] = wsum[w] + sc - v;
    if (t == 1023) part[blockIdx.x] = wsum[15] + sc;
}

__global__ void k_scan2(int* __restrict__ part, int nb) {
    int l = threadIdx.x & 63;
    int run = 0;
    for (int base = 0; base < nb; base += 64) {
        int i = base + l;
        int v = (i < nb) ? part[i] : 0;
        int sc = v;
        #pragma unroll
        for (int off = 1; off < 64; off <<= 1) {
            int y = __shfl_up(sc, off);
            if (l >= off) sc += y;
        }
        if (i < nb) part[i] = run + sc - v;
        run += __shfl(sc, 63);
    }
}

__global__ void k_scan3(int* __restrict__ rowptr, const int* __restrict__ part, int N, int E) {
    int i = blockIdx.x * 256 + threadIdx.x;
    if (i < N) rowptr[i] += part[i >> 10];
    if (i == 0) rowptr[N] = E;
}

__global__ void k_scatter(const int* __restrict__ dst, const int* __restrict__ rowptr,
                          int* __restrict__ cursor, int* __restrict__ csr, int E) {
    int i = blockIdx.x * blockDim.x + threadIdx.x;
    if (i < E) {
        int d = dst[i];
        int pos = rowptr[d] + atomicAdd(&cursor[d], 1);
        csr[pos] = i;
    }
}

// xl1 = x @ Wl1 (bf16 out), xr1 = x @ Wr1 (f32 out)
__global__ __launch_bounds__(256) void k_gemm1(const float* __restrict__ x,
                                               const float* __restrict__ Wl,
                                               const float* __restrict__ Wr,
                                               ushort* __restrict__ xl, float* __restrict__ xr,
                                               int N) {
    __shared__ float xs[32 * 128];
    int r0 = blockIdx.x * 32;
    int t = threadIdx.x;
    for (int i = t * 4; i < 32 * 128; i += 256 * 4) {
        int r = i >> 7;
        float4 v = make_float4(0.f, 0.f, 0.f, 0.f);
        if (r0 + r < N) v = *(const float4*)(&x[(size_t)(r0 + r) * 128 + (i & 127)]);
        *(float4*)(&xs[i]) = v;
    }
    __syncthreads();
    int c = t & 127;
    int rbase = (t >> 7) * 16;
    float accl[16], accr[16];
    #pragma unroll
    for (int r = 0; r < 16; ++r) { accl[r] = 0.f; accr[r] = 0.f; }
    for (int k = 0; k < 128; ++k) {
        float wl = Wl[k * 128 + c];
        float wr = Wr[k * 128 + c];
        #pragma unroll
        for (int r = 0; r < 16; ++r) {
            float xv = xs[(rbase + r) * 128 + k];
            accl[r] += xv * wl;
            accr[r] += xv * wr;
        }
    }
    #pragma unroll
    for (int r = 0; r < 16; ++r) {
        int row = r0 + rbase + r;
        if (row < N) {
            xl[(size_t)row * 128 + c] = f2bf(accl[r]);
            xr[(size_t)row * 128 + c] = accr[r];
        }
    }
}

// LDS-staged edge kernel (persistent, 64 edges per tile):
// qe1[j] = ea[csr[j]]@We1 (bf16 x128), qe2[j] = ea@We2 (f32 x4),
// src_perm[j] = src[csr[j]].
__global__ __launch_bounds__(256) void k_edge(
    const int* __restrict__ csr, const int* __restrict__ src,
    const float* __restrict__ ea, const float* __restrict__ We1,
    const float* __restrict__ We2,
    unsigned* __restrict__ qe1, float* __restrict__ qe2,
    int* __restrict__ src_perm, int E) {
    __shared__ float sea[64][17];  // 17-pad: conflict-free strided reads
    __shared__ int sid[64];
    int t = threadIdx.x, l = t & 63, w = t >> 6;
    // persistent register weights
    float2 we[16];
    #pragma unroll
    for (int k = 0; k < 16; ++k) we[k] = *(const float2*)(We1 + k * 128 + 2 * l);
    float w2[16];
    #pragma unroll
    for (int k = 0; k < 16; ++k) w2[k] = We2[k * 4 + (t & 3)];
    int ntiles = (E + 63) >> 6;
    for (int tile = blockIdx.x; tile < ntiles; tile += gridDim.x) {
        int base = tile << 6;
        __syncthreads();  // previous tile's sea/sid fully consumed
        if (t < 64) {
            int j = base + t;
            int jc = j < E ? j : E - 1;
            int e = csr[jc];
            sid[t] = e;
            if (j < E) src_perm[j] = src[e];
        }
        __syncthreads();
        {   // stage 64 ea rows: 4 threads x float4 per row
            int eidx = t >> 2, q = t & 3;
            int e = sid[eidx];
            float4 v = *(const float4*)(ea + (size_t)e * 16 + q * 4);
            sea[eidx][q * 4 + 0] = v.x;
            sea[eidx][q * 4 + 1] = v.y;
            sea[eidx][q * 4 + 2] = v.z;
            sea[eidx][q * 4 + 3] = v.w;
        }
        __syncthreads();
        {   // qe2: thread t -> edge t>>2, col t&3
            int eidx = t >> 2;
            int j = base + eidx;
            float q = 0.f;
            #pragma unroll
            for (int k = 0; k < 16; ++k) q += sea[eidx][k] * w2[k];
            if (j < E) qe2[(size_t)j * 4 + (t & 3)] = q;
        }
        // qe1: wave w -> edges [w*16, w*16+16), LDS broadcast reads
        #pragma unroll
        for (int i = 0; i < 16; ++i) {
            int eidx = w * 16 + i;
            int j = base + eidx;
            float vx = 0.f, vy = 0.f;
            #pragma unroll
            for (int k = 0; k < 16; ++k) {
                float a = sea[eidx][k];
                vx += a * we[k].x;
                vy += a * we[k].y;
            }
            if (j < E)
                qe1[(size_t)j * 64 + l] = (unsigned)f2bf(vx) | ((unsigned)f2bf(vy) << 16);
        }
    }
}

// layer 1 fused (wave per node, lane l owns channels 2l,2l+1), unroll-4,
// self-loop term = running mean of qe1 over incoming edges.
__global__ __launch_bounds__(256) void k_fused1_q(
    const int* __restrict__ rowptr, const int* __restrict__ src_perm,
    const ushort* __restrict__ xl_bf, const float* __restrict__ xr,
    const unsigned* __restrict__ qe1, const float* __restrict__ att,
    const float* __restrict__ Wl2, const float* __restrict__ Wr2,
    float* __restrict__ xl2, float* __restrict__ xr2, int N) {
    int t = threadIdx.x, l = t & 63;
    int n = (blockIdx.x * 256 + t) >> 6;
    if (n >= N) return;
    const float RLN2 = 1.44269504f;
    float2 av = *(const float2*)(att + 2 * l);
    av.x *= RLN2; av.y *= RLN2;
    float2 xrv = *(const float2*)(xr + (size_t)n * 128 + 2 * l);
    int rs = rowptr[n], re = rowptr[n + 1];
    int deg = re - rs;
    float acc0 = 0.f, acc1 = 0.f, den = 0.f, mq0 = 0.f, mq1 = 0.f;
    for (int base = 0; base < deg; base += 4) {
        int rowA[4];
        float mask[4];
        #pragma unroll
        for (int c = 0; c < 4; ++c) {
            int slot = base + c;
            bool valid = slot < deg;
            mask[c] = valid ? 1.f : 0.f;
            rowA[c] = valid ? rs + slot : rs;
        }
        int sA[4];
        #pragma unroll
        for (int c = 0; c < 4; ++c) sA[c] = src_perm[rowA[c]];
        unsigned qw[4];
        #pragma unroll
        for (int c = 0; c < 4; ++c) qw[c] = qe1[(size_t)rowA[c] * 64 + l];
        unsigned xw[4];
        #pragma unroll
        for (int c = 0; c < 4; ++c)
            xw[c] = *(const unsigned*)(xl_bf + (size_t)sA[c] * 128 + 2 * l);
        #pragma unroll
        for (int c = 0; c < 4; ++c) {
            float q0 = __uint_as_float(qw[c] << 16);
            float q1 = __uint_as_float(qw[c] & 0xffff0000u);
            float xl0 = __uint_as_float(xw[c] << 16);
            float xl1 = __uint_as_float(xw[c] & 0xffff0000u);
            float vx = xrv.x + xl0 + q0;
            float vy = xrv.y + xl1 + q1;
            vx = fmaxf(vx, 0.2f * vx);
            vy = fmaxf(vy, 0.2f * vy);
            float p = row_sum16(av.x * vx + av.y * vy);
            float w = exp2f(p) * mask[c];
            acc0 += w * xl0;
            acc1 += w * xl1;
            den += w;
            mq0 += mask[c] * q0;
            mq1 += mask[c] * q1;
        }
    }
    {   // self loop: qe_self = mean of incoming qe1
        float inv = 1.f / (float)(deg > 1 ? deg : 1);
        float q0 = mq0 * inv, q1 = mq1 * inv;
        unsigned xw = *(const unsigned*)(xl_bf + (size_t)n * 128 + 2 * l);
        float xl0 = __uint_as_float(xw << 16);
        float xl1 = __uint_as_float(xw & 0xffff0000u);
        float vx = xrv.x + xl0 + q0;
        float vy = xrv.y + xl1 + q1;
        vx = fmaxf(vx, 0.2f * vx);
        vy = fmaxf(vy, 0.2f * vy);
        float p = row_sum16(av.x * vx + av.y * vy);
        float w = exp2f(p);
        acc0 += w * xl0;
        acc1 += w * xl1;
        den += w;
    }
    float rdn = 1.f / (den + 1e-16f);
    float h0 = acc0 * rdn, h1 = acc1 * rdn;
    h0 = h0 > 0.f ? h0 : 0.01f * h0;
    h1 = h1 > 0.f ? h1 : 0.01f * h1;
    float4 wla = *(const float4*)(Wl2 + (size_t)(2 * l) * 4);
    float4 wlb = *(const float4*)(Wl2 + (size_t)(2 * l + 1) * 4);
    float4 wra = *(const float4*)(Wr2 + (size_t)(2 * l) * 4);
    float4 wrb = *(const float4*)(Wr2 + (size_t)(2 * l + 1) * 4);
    float q0 = red64(h0 * wla.x + h1 * wlb.x);
    float q1 = red64(h0 * wla.y + h1 * wlb.y);
    float q2 = red64(h0 * wla.z + h1 * wlb.z);
    float q3 = red64(h0 * wla.w + h1 * wlb.w);
    float q4 = red64(h0 * wra.x + h1 * wrb.x);
    float q5 = red64(h0 * wra.y + h1 * wrb.y);
    float q6 = red64(h0 * wra.z + h1 * wrb.z);
    float q7 = red64(h0 * wra.w + h1 * wrb.w);
    if (l == 0) {
        *(float4*)(xl2 + (size_t)n * 4) = make_float4(q0, q1, q2, q3);
        *(float4*)(xr2 + (size_t)n * 4) = make_float4(q4, q5, q6, q7);
    }
}

// layer 2 fused: 16 lanes per node, self-term = in-loop mean of qe2
__global__ __launch_bounds__(256) void k_fused2_q(
    const int* __restrict__ rowptr, const int* __restrict__ src_perm,
    const float* __restrict__ xl2, const float* __restrict__ xr2,
    const float* __restrict__ qe2, const float* __restrict__ att2,
    float* __restrict__ out, int N) {
    int t = threadIdx.x, l = t & 63, g = l & 15;
    int node = (((blockIdx.x * 256 + t) >> 6) << 2) + (l >> 4);
    if (node >= N) return;
    int rs = rowptr[node], re = rowptr[node + 1];
    int deg = re - rs;
    float4 xrv = *(const float4*)(xr2 + (size_t)node * 4);
    const float RLN2 = 1.44269504f;
    float a0 = att2[0] * RLN2, a1 = att2[1] * RLN2;
    float a2 = att2[2] * RLN2, a3 = att2[3] * RLN2;
    float ac0 = 0.f, ac1 = 0.f, ac2 = 0.f, ac3 = 0.f;
    float dn0 = 0.f, dn1 = 0.f, dn2 = 0.f, dn3 = 0.f;
    float mq0 = 0.f, mq1 = 0.f, mq2 = 0.f, mq3 = 0.f;
    for (int slot = g; slot < deg; slot += 16) {
        int row = rs + slot;
        int s = src_perm[row];
        float4 q = *(const float4*)(qe2 + (size_t)row * 4);
        float4 xv = *(const float4*)(xl2 + (size_t)s * 4);
        float v0 = xv.x + xrv.x + q.x; v0 = fmaxf(v0, 0.2f * v0);
        float v1 = xv.y + xrv.y + q.y; v1 = fmaxf(v1, 0.2f * v1);
        float v2 = xv.z + xrv.z + q.z; v2 = fmaxf(v2, 0.2f * v2);
        float v3 = xv.w + xrv.w + q.w; v3 = fmaxf(v3, 0.2f * v3);
        float w0 = exp2f(v0 * a0); ac0 += w0 * xv.x; dn0 += w0;
        float w1 = exp2f(v1 * a1); ac1 += w1 * xv.y; dn1 += w1;
        float w2 = exp2f(v2 * a2); ac2 += w2 * xv.z; dn2 += w2;
        float w3 = exp2f(v3 * a3); ac3 += w3 * xv.w; dn3 += w3;
        mq0 += q.x; mq1 += q.y; mq2 += q.z; mq3 += q.w;
    }
    ac0 = row_sum16(ac0); ac1 = row_sum16(ac1);
    ac2 = row_sum16(ac2); ac3 = row_sum16(ac3);
    dn0 = row_sum16(dn0); dn1 = row_sum16(dn1);
    dn2 = row_sum16(dn2); dn3 = row_sum16(dn3);
    mq0 = row_sum16(mq0); mq1 = row_sum16(mq1);
    mq2 = row_sum16(mq2); mq3 = row_sum16(mq3);
    {   // self loop (uniform across the 16-lane group)
        float inv = 1.f / (float)(deg > 1 ? deg : 1);
        float4 xv = *(const float4*)(xl2 + (size_t)node * 4);
        float v0 = xv.x + xrv.x + mq0 * inv; v0 = fmaxf(v0, 0.2f * v0);
        float v1 = xv.y + xrv.y + mq1 * inv; v1 = fmaxf(v1, 0.2f * v1);
        float v2 = xv.z + xrv.z + mq2 * inv; v2 = fmaxf(v2, 0.2f * v2);
        float v3 = xv.w + xrv.w + mq3 * inv; v3 = fmaxf(v3, 0.2f * v3);
        float w0 = exp2f(v0 * a0); ac0 += w0 * xv.x; dn0 += w0;
        float w1 = exp2f(v1 * a1); ac1 += w1 * xv.y; dn1 += w1;
        float w2 = exp2f(v2 * a2); ac2 += w2 * xv.z; dn2 += w2;
        float w3 = exp2f(v3 * a3); ac3 += w3 * xv.w; dn3 += w3;
    }
    if (g == 0) {
        float r = ac0 / (dn0 + 1e-16f) + ac1 / (dn1 + 1e-16f)
                + ac2 / (dn2 + 1e-16f) + ac3 / (dn3 + 1e-16f);
        out[node] = r * 0.25f;
    }
}

extern "C" void kernel_launch(void* const* d_in, const int* in_sizes, int n_in,
                              void* d_out, int out_size, void* d_ws, size_t ws_size,
                              hipStream_t stream) {
    const float* x         = (const float*)d_in[0];
    const int*   edge_index= (const int*)d_in[1];
    const float* edge_attr = (const float*)d_in[2];
    const float* Wl1       = (const float*)d_in[3];
    const float* Wr1       = (const float*)d_in[4];
    const float* We1       = (const float*)d_in[5];
    const float* att1      = (const float*)d_in[6];
    const float* Wl2       = (const float*)d_in[7];
    const float* Wr2       = (const float*)d_in[8];
    const float* We2       = (const float*)d_in[9];
    const float* att2      = (const float*)d_in[10];
    float* outp = (float*)d_out;

    const int F = 128, HC = 128;
    int N = in_sizes[0] / F;
    int E = in_sizes[1] / 2;
    const int* src = edge_index;
    const int* dst = edge_index + E;

    char* ws = (char*)d_ws;
    size_t off = 0;
    auto alloc = [&](size_t bytes) {
        char* p = ws + off;
        off += (bytes + 255) & ~(size_t)255;
        return p;
    };
    int*      deg      = (int*)alloc((size_t)N * 4);
    int*      cursor   = (int*)alloc((size_t)N * 4);
    int*      rowptr   = (int*)alloc((size_t)(N + 1) * 4);
    int*      part     = (int*)alloc(((size_t)N / 1024 + 2) * 4);
    int*      csr      = (int*)alloc((size_t)E * 4);
    ushort*   xl_bf    = (ushort*)alloc((size_t)N * HC * 2);
    float*    xr1      = (float*)alloc((size_t)N * HC * 4);
    float*    xl2      = (float*)alloc((size_t)N * 4 * 4);
    float*    xr2      = (float*)alloc((size_t)N * 4 * 4);
    int*      src_perm = (int*)alloc((size_t)E * 4);
    float*    qe2      = (float*)alloc((size_t)E * 4 * 4);
    unsigned* qe1      = (unsigned*)alloc((size_t)E * 64 * 4);

    int eb = (E + 255) / 256;
    int nb = (N + 1023) / 1024;

    hipMemsetAsync(deg, 0, (size_t)((char*)rowptr - (char*)deg), stream);
    k_count_deg<<<eb, 256, 0, stream>>>(dst, deg, E);
    k_scan1<<<nb, 1024, 0, stream>>>(deg, rowptr, part, N);
    k_scan2<<<1, 64, 0, stream>>>(part, nb);
    k_scan3<<<(N + 255) / 256, 256, 0, stream>>>(rowptr, part, N, E);
    k_scatter<<<eb, 256, 0, stream>>>(dst, rowptr, cursor, csr, E);
    k_gemm1<<<(N + 31) / 32, 256, 0, stream>>>(x, Wl1, Wr1, xl_bf, xr1, N);
    k_edge<<<2048, 256, 0, stream>>>(csr, src, edge_attr, We1, We2,
                                     qe1, qe2, src_perm, E);
    k_fused1_q<<<(N + 3) / 4, 256, 0, stream>>>(rowptr, src_perm, xl_bf, xr1, qe1,
                                                att1, Wl2, Wr2, xl2, xr2, N);
    k_fused2_q<<<(N + 15) / 16, 256, 0, stream>>>(rowptr, src_perm, xl2, xr2, qe2,
                                                  att2, outp, N);
}

// Round 8
// 359.243 us; speedup vs baseline: 2.4908x; 1.1082x over previous
//
#include <hip/hip_runtime.h>
#include <math.h>

// ---------------------------------------------------------------------------
// GATv2 x2 on MI355X.
// Path:
//   memset -> count_deg -> scan1/2/3 -> scatter(CSR) -> gemm1(xl bf16, xr f32)
//   -> k_edge (LDS-staged 64-edge tiles: qe1=ea@We1 bf16 CSR-order, qe2, src_perm)
//   -> k_fused1_q (softmax+aggregate+lrelu+gemv2; self-term = in-loop qe1 mean)
//   -> k_fused2_q (softmax+aggregate+head-mean;   self-term = in-loop qe2 mean)
// gemm1: 64-row tiles, float4 LDS reads over k (ds_read_b128), 84% FMA mix.
// ---------------------------------------------------------------------------

static __device__ __forceinline__ ushort f2bf(float f) {
    unsigned u = __float_as_uint(f);
    unsigned r = (u + 0x7fffu + ((u >> 16) & 1u)) >> 16;  // RNE
    return (ushort)r;
}

// sum across each 16-lane row via DPP row_ror (pure VALU, no DS)
static __device__ __forceinline__ float row_sum16(float x) {
    x += __int_as_float(__builtin_amdgcn_update_dpp(0, __float_as_int(x), 0x121, 0xf, 0xf, true));
    x += __int_as_float(__builtin_amdgcn_update_dpp(0, __float_as_int(x), 0x122, 0xf, 0xf, true));
    x += __int_as_float(__builtin_amdgcn_update_dpp(0, __float_as_int(x), 0x124, 0xf, 0xf, true));
    x += __int_as_float(__builtin_amdgcn_update_dpp(0, __float_as_int(x), 0x128, 0xf, 0xf, true));
    return x;
}

static __device__ __forceinline__ float red64(float x) {  // 64-lane sum
    x = row_sum16(x);
    x += __shfl_xor(x, 16);
    x += __shfl_xor(x, 32);
    return x;
}

__global__ void k_count_deg(const int* __restrict__ dst, int* __restrict__ deg, int E) {
    int i = blockIdx.x * blockDim.x + threadIdx.x;
    if (i < E) atomicAdd(&deg[dst[i]], 1);
}

__global__ __launch_bounds__(1024) void k_scan1(const int* __restrict__ deg,
                                                int* __restrict__ rowptr,
                                                int* __restrict__ part, int N) {
    __shared__ int wsum[16];
    int t = threadIdx.x, l = t & 63, w = t >> 6;
    int i = blockIdx.x * 1024 + t;
    int v = (i < N) ? deg[i] : 0;
    int sc = v;
    #pragma unroll
    for (int off = 1; off < 64; off <<= 1) {
        int y = __shfl_up(sc, off);
        if (l >= off) sc += y;
    }
    if (l == 63) wsum[w] = sc;
    __syncthreads();
    if (w == 0) {
        int pv = (l < 16) ? wsum[l] : 0;
        int psc = pv;
        #pragma unroll
        for (int off = 1; off < 16; off <<= 1) {
            int y = __shfl_up(psc, off);
            if (l >= off) psc += y;
        }
        if (l < 16) wsum[l] = psc - pv;
    }
    __syncthreads();
    if (i < N) rowptr[i] = wsum[w] + sc - v;
    if (t == 1023) part[blockIdx.x] = wsum[15] + sc;
}

__global__ void k_scan2(int* __restrict__ part, int nb) {
    int l = threadIdx.x & 63;
    int run = 0;
    for (int base = 0; base < nb; base += 64) {
        int i = base + l;
        int v = (i < nb) ? part[i] : 0;
        int sc = v;
        #pragma unroll
        for (int off = 1; off < 64; off <<= 1) {
            int y = __shfl_up(sc, off);
            if (l >= off) sc += y;
        }
        if (i < nb) part[i] = run + sc - v;
        run += __shfl(sc, 63);
    }
}

__global__ void k_scan3(int* __restrict__ rowptr, const int* __restrict__ part, int N, int E) {
    int i = blockIdx.x * 256 + threadIdx.x;
    if (i < N) rowptr[i] += part[i >> 10];
    if (i == 0) rowptr[N] = E;
}

__global__ void k_scatter(const int* __restrict__ dst, const int* __restrict__ rowptr,
                          int* __restrict__ cursor, int* __restrict__ csr, int E) {
    int i = blockIdx.x * blockDim.x + threadIdx.x;
    if (i < E) {
        int d = dst[i];
        int pos = rowptr[d] + atomicAdd(&cursor[d], 1);
        csr[pos] = i;
    }
}

// xl1 = x @ Wl1 (bf16 out), xr1 = x @ Wr1 (f32 out). 64-row tiles,
// float4 LDS reads across k.
__global__ __launch_bounds__(256) void k_gemm1(const float* __restrict__ x,
                                               const float* __restrict__ Wl,
                                               const float* __restrict__ Wr,
                                               ushort* __restrict__ xl, float* __restrict__ xr,
                                               int N) {
    __shared__ float xs[64 * 128];  // 32 KB
    int r0 = blockIdx.x * 64;
    int t = threadIdx.x;
    for (int i = t * 4; i < 64 * 128; i += 256 * 4) {
        int r = i >> 7;
        float4 v = make_float4(0.f, 0.f, 0.f, 0.f);
        if (r0 + r < N) v = *(const float4*)(&x[(size_t)(r0 + r) * 128 + (i & 127)]);
        *(float4*)(&xs[i]) = v;
    }
    __syncthreads();
    int c = t & 127;
    int rbase = (t >> 7) * 32;  // 0 or 32
    float accl[32], accr[32];
    #pragma unroll
    for (int r = 0; r < 32; ++r) { accl[r] = 0.f; accr[r] = 0.f; }
    for (int k = 0; k < 128; k += 4) {
        float wl0 = Wl[(k + 0) * 128 + c];
        float wl1 = Wl[(k + 1) * 128 + c];
        float wl2 = Wl[(k + 2) * 128 + c];
        float wl3 = Wl[(k + 3) * 128 + c];
        float wr0 = Wr[(k + 0) * 128 + c];
        float wr1 = Wr[(k + 1) * 128 + c];
        float wr2 = Wr[(k + 2) * 128 + c];
        float wr3 = Wr[(k + 3) * 128 + c];
        #pragma unroll
        for (int r = 0; r < 32; ++r) {
            float4 xv = *(const float4*)(&xs[(rbase + r) * 128 + k]);
            accl[r] += xv.x * wl0 + xv.y * wl1 + xv.z * wl2 + xv.w * wl3;
            accr[r] += xv.x * wr0 + xv.y * wr1 + xv.z * wr2 + xv.w * wr3;
        }
    }
    #pragma unroll
    for (int r = 0; r < 32; ++r) {
        int row = r0 + rbase + r;
        if (row < N) {
            xl[(size_t)row * 128 + c] = f2bf(accl[r]);
            xr[(size_t)row * 128 + c] = accr[r];
        }
    }
}

// LDS-staged edge kernel (persistent, 64 edges per tile):
// qe1[j] = ea[csr[j]]@We1 (bf16 x128), qe2[j] = ea@We2 (f32 x4),
// src_perm[j] = src[csr[j]].
__global__ __launch_bounds__(256) void k_edge(
    const int* __restrict__ csr, const int* __restrict__ src,
    const float* __restrict__ ea, const float* __restrict__ We1,
    const float* __restrict__ We2,
    unsigned* __restrict__ qe1, float* __restrict__ qe2,
    int* __restrict__ src_perm, int E) {
    __shared__ float sea[64][17];  // 17-pad: conflict-free strided reads
    __shared__ int sid[64];
    int t = threadIdx.x, l = t & 63, w = t >> 6;
    // persistent register weights
    float2 we[16];
    #pragma unroll
    for (int k = 0; k < 16; ++k) we[k] = *(const float2*)(We1 + k * 128 + 2 * l);
    float w2[16];
    #pragma unroll
    for (int k = 0; k < 16; ++k) w2[k] = We2[k * 4 + (t & 3)];
    int ntiles = (E + 63) >> 6;
    for (int tile = blockIdx.x; tile < ntiles; tile += gridDim.x) {
        int base = tile << 6;
        __syncthreads();  // previous tile's sea/sid fully consumed
        if (t < 64) {
            int j = base + t;
            int jc = j < E ? j : E - 1;
            int e = csr[jc];
            sid[t] = e;
            if (j < E) src_perm[j] = src[e];
        }
        __syncthreads();
        {   // stage 64 ea rows: 4 threads x float4 per row
            int eidx = t >> 2, q = t & 3;
            int e = sid[eidx];
            float4 v = *(const float4*)(ea + (size_t)e * 16 + q * 4);
            sea[eidx][q * 4 + 0] = v.x;
            sea[eidx][q * 4 + 1] = v.y;
            sea[eidx][q * 4 + 2] = v.z;
            sea[eidx][q * 4 + 3] = v.w;
        }
        __syncthreads();
        {   // qe2: thread t -> edge t>>2, col t&3
            int eidx = t >> 2;
            int j = base + eidx;
            float q = 0.f;
            #pragma unroll
            for (int k = 0; k < 16; ++k) q += sea[eidx][k] * w2[k];
            if (j < E) qe2[(size_t)j * 4 + (t & 3)] = q;
        }
        // qe1: wave w -> edges [w*16, w*16+16), LDS broadcast reads
        #pragma unroll
        for (int i = 0; i < 16; ++i) {
            int eidx = w * 16 + i;
            int j = base + eidx;
            float vx = 0.f, vy = 0.f;
            #pragma unroll
            for (int k = 0; k < 16; ++k) {
                float a = sea[eidx][k];
                vx += a * we[k].x;
                vy += a * we[k].y;
            }
            if (j < E)
                qe1[(size_t)j * 64 + l] = (unsigned)f2bf(vx) | ((unsigned)f2bf(vy) << 16);
        }
    }
}

// layer 1 fused (wave per node, lane l owns channels 2l,2l+1), unroll-4,
// self-loop term = running mean of qe1 over incoming edges.
__global__ __launch_bounds__(256) void k_fused1_q(
    const int* __restrict__ rowptr, const int* __restrict__ src_perm,
    const ushort* __restrict__ xl_bf, const float* __restrict__ xr,
    const unsigned* __restrict__ qe1, const float* __restrict__ att,
    const float* __restrict__ Wl2, const float* __restrict__ Wr2,
    float* __restrict__ xl2, float* __restrict__ xr2, int N) {
    int t = threadIdx.x, l = t & 63;
    int n = (blockIdx.x * 256 + t) >> 6;
    if (n >= N) return;
    const float RLN2 = 1.44269504f;
    float2 av = *(const float2*)(att + 2 * l);
    av.x *= RLN2; av.y *= RLN2;
    float2 xrv = *(const float2*)(xr + (size_t)n * 128 + 2 * l);
    int rs = rowptr[n], re = rowptr[n + 1];
    int deg = re - rs;
    float acc0 = 0.f, acc1 = 0.f, den = 0.f, mq0 = 0.f, mq1 = 0.f;
    for (int base = 0; base < deg; base += 4) {
        int rowA[4];
        float mask[4];
        #pragma unroll
        for (int c = 0; c < 4; ++c) {
            int slot = base + c;
            bool valid = slot < deg;
            mask[c] = valid ? 1.f : 0.f;
            rowA[c] = valid ? rs + slot : rs;
        }
        int sA[4];
        #pragma unroll
        for (int c = 0; c < 4; ++c) sA[c] = src_perm[rowA[c]];
        unsigned qw[4];
        #pragma unroll
        for (int c = 0; c < 4; ++c) qw[c] = qe1[(size_t)rowA[c] * 64 + l];
        unsigned xw[4];
        #pragma unroll
        for (int c = 0; c < 4; ++c)
            xw[c] = *(const unsigned*)(xl_bf + (size_t)sA[c] * 128 + 2 * l);
        #pragma unroll
        for (int c = 0; c < 4; ++c) {
            float q0 = __uint_as_float(qw[c] << 16);
            float q1 = __uint_as_float(qw[c] & 0xffff0000u);
            float xl0 = __uint_as_float(xw[c] << 16);
            float xl1 = __uint_as_float(xw[c] & 0xffff0000u);
            float vx = xrv.x + xl0 + q0;
            float vy = xrv.y + xl1 + q1;
            vx = fmaxf(vx, 0.2f * vx);
            vy = fmaxf(vy, 0.2f * vy);
            float p = row_sum16(av.x * vx + av.y * vy);
            float w = exp2f(p) * mask[c];
            acc0 += w * xl0;
            acc1 += w * xl1;
            den += w;
            mq0 += mask[c] * q0;
            mq1 += mask[c] * q1;
        }
    }
    {   // self loop: qe_self = mean of incoming qe1
        float inv = 1.f / (float)(deg > 1 ? deg : 1);
        float q0 = mq0 * inv, q1 = mq1 * inv;
        unsigned xw = *(const unsigned*)(xl_bf + (size_t)n * 128 + 2 * l);
        float xl0 = __uint_as_float(xw << 16);
        float xl1 = __uint_as_float(xw & 0xffff0000u);
        float vx = xrv.x + xl0 + q0;
        float vy = xrv.y + xl1 + q1;
        vx = fmaxf(vx, 0.2f * vx);
        vy = fmaxf(vy, 0.2f * vy);
        float p = row_sum16(av.x * vx + av.y * vy);
        float w = exp2f(p);
        acc0 += w * xl0;
        acc1 += w * xl1;
        den += w;
    }
    float rdn = 1.f / (den + 1e-16f);
    float h0 = acc0 * rdn, h1 = acc1 * rdn;
    h0 = h0 > 0.f ? h0 : 0.01f * h0;
    h1 = h1 > 0.f ? h1 : 0.01f * h1;
    float4 wla = *(const float4*)(Wl2 + (size_t)(2 * l) * 4);
    float4 wlb = *(const float4*)(Wl2 + (size_t)(2 * l + 1) * 4);
    float4 wra = *(const float4*)(Wr2 + (size_t)(2 * l) * 4);
    float4 wrb = *(const float4*)(Wr2 + (size_t)(2 * l + 1) * 4);
    float q0 = red64(h0 * wla.x + h1 * wlb.x);
    float q1 = red64(h0 * wla.y + h1 * wlb.y);
    float q2 = red64(h0 * wla.z + h1 * wlb.z);
    float q3 = red64(h0 * wla.w + h1 * wlb.w);
    float q4 = red64(h0 * wra.x + h1 * wrb.x);
    float q5 = red64(h0 * wra.y + h1 * wrb.y);
    float q6 = red64(h0 * wra.z + h1 * wrb.z);
    float q7 = red64(h0 * wra.w + h1 * wrb.w);
    if (l == 0) {
        *(float4*)(xl2 + (size_t)n * 4) = make_float4(q0, q1, q2, q3);
        *(float4*)(xr2 + (size_t)n * 4) = make_float4(q4, q5, q6, q7);
    }
}

// layer 2 fused: 16 lanes per node, self-term = in-loop mean of qe2
__global__ __launch_bounds__(256) void k_fused2_q(
    const int* __restrict__ rowptr, const int* __restrict__ src_perm,
    const float* __restrict__ xl2, const float* __restrict__ xr2,
    const float* __restrict__ qe2, const float* __restrict__ att2,
    float* __restrict__ out, int N) {
    int t = threadIdx.x, l = t & 63, g = l & 15;
    int node = (((blockIdx.x * 256 + t) >> 6) << 2) + (l >> 4);
    if (node >= N) return;
    int rs = rowptr[node], re = rowptr[node + 1];
    int deg = re - rs;
    float4 xrv = *(const float4*)(xr2 + (size_t)node * 4);
    const float RLN2 = 1.44269504f;
    float a0 = att2[0] * RLN2, a1 = att2[1] * RLN2;
    float a2 = att2[2] * RLN2, a3 = att2[3] * RLN2;
    float ac0 = 0.f, ac1 = 0.f, ac2 = 0.f, ac3 = 0.f;
    float dn0 = 0.f, dn1 = 0.f, dn2 = 0.f, dn3 = 0.f;
    float mq0 = 0.f, mq1 = 0.f, mq2 = 0.f, mq3 = 0.f;
    for (int slot = g; slot < deg; slot += 16) {
        int row = rs + slot;
        int s = src_perm[row];
        float4 q = *(const float4*)(qe2 + (size_t)row * 4);
        float4 xv = *(const float4*)(xl2 + (size_t)s * 4);
        float v0 = xv.x + xrv.x + q.x; v0 = fmaxf(v0, 0.2f * v0);
        float v1 = xv.y + xrv.y + q.y; v1 = fmaxf(v1, 0.2f * v1);
        float v2 = xv.z + xrv.z + q.z; v2 = fmaxf(v2, 0.2f * v2);
        float v3 = xv.w + xrv.w + q.w; v3 = fmaxf(v3, 0.2f * v3);
        float w0 = exp2f(v0 * a0); ac0 += w0 * xv.x; dn0 += w0;
        float w1 = exp2f(v1 * a1); ac1 += w1 * xv.y; dn1 += w1;
        float w2 = exp2f(v2 * a2); ac2 += w2 * xv.z; dn2 += w2;
        float w3 = exp2f(v3 * a3); ac3 += w3 * xv.w; dn3 += w3;
        mq0 += q.x; mq1 += q.y; mq2 += q.z; mq3 += q.w;
    }
    ac0 = row_sum16(ac0); ac1 = row_sum16(ac1);
    ac2 = row_sum16(ac2); ac3 = row_sum16(ac3);
    dn0 = row_sum16(dn0); dn1 = row_sum16(dn1);
    dn2 = row_sum16(dn2); dn3 = row_sum16(dn3);
    mq0 = row_sum16(mq0); mq1 = row_sum16(mq1);
    mq2 = row_sum16(mq2); mq3 = row_sum16(mq3);
    {   // self loop (uniform across the 16-lane group)
        float inv = 1.f / (float)(deg > 1 ? deg : 1);
        float4 xv = *(const float4*)(xl2 + (size_t)node * 4);
        float v0 = xv.x + xrv.x + mq0 * inv; v0 = fmaxf(v0, 0.2f * v0);
        float v1 = xv.y + xrv.y + mq1 * inv; v1 = fmaxf(v1, 0.2f * v1);
        float v2 = xv.z + xrv.z + mq2 * inv; v2 = fmaxf(v2, 0.2f * v2);
        float v3 = xv.w + xrv.w + mq3 * inv; v3 = fmaxf(v3, 0.2f * v3);
        float w0 = exp2f(v0 * a0); ac0 += w0 * xv.x; dn0 += w0;
        float w1 = exp2f(v1 * a1); ac1 += w1 * xv.y; dn1 += w1;
        float w2 = exp2f(v2 * a2); ac2 += w2 * xv.z; dn2 += w2;
        float w3 = exp2f(v3 * a3); ac3 += w3 * xv.w; dn3 += w3;
    }
    if (g == 0) {
        float r = ac0 / (dn0 + 1e-16f) + ac1 / (dn1 + 1e-16f)
                + ac2 / (dn2 + 1e-16f) + ac3 / (dn3 + 1e-16f);
        out[node] = r * 0.25f;
    }
}

extern "C" void kernel_launch(void* const* d_in, const int* in_sizes, int n_in,
                              void* d_out, int out_size, void* d_ws, size_t ws_size,
                              hipStream_t stream) {
    const float* x         = (const float*)d_in[0];
    const int*   edge_index= (const int*)d_in[1];
    const float* edge_attr = (const float*)d_in[2];
    const float* Wl1       = (const float*)d_in[3];
    const float* Wr1       = (const float*)d_in[4];
    const float* We1       = (const float*)d_in[5];
    const float* att1      = (const float*)d_in[6];
    const float* Wl2       = (const float*)d_in[7];
    const float* Wr2       = (const float*)d_in[8];
    const float* We2       = (const float*)d_in[9];
    const float* att2      = (const float*)d_in[10];
    float* outp = (float*)d_out;

    const int F = 128, HC = 128;
    int N = in_sizes[0] / F;
    int E = in_sizes[1] / 2;
    const int* src = edge_index;
    const int* dst = edge_index + E;

    char* ws = (char*)d_ws;
    size_t off = 0;
    auto alloc = [&](size_t bytes) {
        char* p = ws + off;
        off += (bytes + 255) & ~(size_t)255;
        return p;
    };
    int*      deg      = (int*)alloc((size_t)N * 4);
    int*      cursor   = (int*)alloc((size_t)N * 4);
    int*      rowptr   = (int*)alloc((size_t)(N + 1) * 4);
    int*      part     = (int*)alloc(((size_t)N / 1024 + 2) * 4);
    int*      csr      = (int*)alloc((size_t)E * 4);
    ushort*   xl_bf    = (ushort*)alloc((size_t)N * HC * 2);
    float*    xr1      = (float*)alloc((size_t)N * HC * 4);
    float*    xl2      = (float*)alloc((size_t)N * 4 * 4);
    float*    xr2      = (float*)alloc((size_t)N * 4 * 4);
    int*      src_perm = (int*)alloc((size_t)E * 4);
    float*    qe2      = (float*)alloc((size_t)E * 4 * 4);
    unsigned* qe1      = (unsigned*)alloc((size_t)E * 64 * 4);

    int eb = (E + 255) / 256;
    int nb = (N + 1023) / 1024;

    hipMemsetAsync(deg, 0, (size_t)((char*)rowptr - (char*)deg), stream);
    k_count_deg<<<eb, 256, 0, stream>>>(dst, deg, E);
    k_scan1<<<nb, 1024, 0, stream>>>(deg, rowptr, part, N);
    k_scan2<<<1, 64, 0, stream>>>(part, nb);
    k_scan3<<<(N + 255) / 256, 256, 0, stream>>>(rowptr, part, N, E);
    k_scatter<<<eb, 256, 0, stream>>>(dst, rowptr, cursor, csr, E);
    k_gemm1<<<(N + 63) / 64, 256, 0, stream>>>(x, Wl1, Wr1, xl_bf, xr1, N);
    k_edge<<<2048, 256, 0, stream>>>(csr, src, edge_attr, We1, We2,
                                     qe1, qe2, src_perm, E);
    k_fused1_q<<<(N + 3) / 4, 256, 0, stream>>>(rowptr, src_perm, xl_bf, xr1, qe1,
                                                att1, Wl2, Wr2, xl2, xr2, N);
    k_fused2_q<<<(N + 15) / 16, 256, 0, stream>>>(rowptr, src_perm, xl2, xr2, qe2,
                                                  att2, outp, N);
}